// Round 22
// baseline (114.079 us; speedup 1.0000x reference)
//
#include <hip/hip_runtime.h>
#include <hip/hip_bf16.h>
#include <math.h>

typedef short bf16x8 __attribute__((ext_vector_type(8)));
typedef float f32x4 __attribute__((ext_vector_type(4)));
typedef unsigned short u16;
typedef u16 u16x4 __attribute__((ext_vector_type(4)));
typedef u16 u16x8 __attribute__((ext_vector_type(8)));

#define DEV static __device__ __forceinline__
#define GLB __attribute__((address_space(1)))
#define LDS __attribute__((address_space(3)))

#if defined(__has_builtin)
#if __has_builtin(__builtin_amdgcn_fdot2_f32_bf16)
#define HAS_BF16_DOT2 1
#endif
#endif

#ifdef HAS_BF16_DOT2
typedef __bf16 bf16x2 __attribute__((ext_vector_type(2)));
#endif

DEV float bf2f(u16 u) { union { unsigned int i; float f; } v; v.i = ((unsigned int)u) << 16; return v.f; }
DEV u16 f2bf(float f) {
  union { float fl; unsigned int i; } v; v.fl = f;
  return (u16)((v.i + 0x7FFFu + ((v.i >> 16) & 1u)) >> 16);
}

DEV bf16x8 asbf(u16x8 v) { union { u16x8 u; bf16x8 b; } c; c.u = v; return c.b; }

// keep a loaded vector alive/materialized at this program point (forces batched issue)
DEV void pinv(const u16x8& v) { asm volatile("" :: "v"(v)); }

// 8-element bf16 dot: acc += sum_e k[e]*q[e]
DEV float dot8(u16x8 k, u16x8 q, float acc) {
#ifdef HAS_BF16_DOT2
  union { u16x8 u; bf16x2 b[4]; } ku, qu;
  ku.u = k; qu.u = q;
#pragma unroll
  for (int e = 0; e < 4; ++e)
    acc = __builtin_amdgcn_fdot2_f32_bf16(ku.b[e], qu.b[e], acc, false);
#else
#pragma unroll
  for (int e = 0; e < 8; ++e) acc = fmaf(bf2f(k[e]), bf2f(q[e]), acc);
#endif
  return acc;
}

// ---------------- prep (blocks 0..4357) + weight transpose (blocks 4358..8453) ----------------
__global__ __launch_bounds__(256) void prepw_kernel(
    const float* __restrict__ x, const float* __restrict__ bq,
    const float* __restrict__ bk, const float* __restrict__ bv,
    float* __restrict__ biascat, float* __restrict__ cosT, float* __restrict__ sinT,
    u16* __restrict__ xbf,
    const float* __restrict__ wq, const float* __restrict__ wk,
    const float* __restrict__ wv, const float* __restrict__ wo,
    u16* __restrict__ wcat, u16* __restrict__ wot)
{
  __shared__ float tile[32][33];
  if (blockIdx.x < 4358) {
    int idx = blockIdx.x * 256 + threadIdx.x;
    const int NX = (4096 * 1024) / 4;
    if (idx < NX) {
      const float4 v = ((const float4*)x)[idx];
      u16x4 o;
      o[0] = f2bf(v.x); o[1] = f2bf(v.y); o[2] = f2bf(v.z); o[3] = f2bf(v.w);
      *((u16x4*)xbf + idx) = o;
    } else if (idx < NX + 1536) {
      int n = idx - NX;
      biascat[n] = (n < 1024) ? bq[n] : (n < 1280 ? bk[n - 1024] : bv[n - 1280]);
    } else if (idx < NX + 1536 + 65536) {
      int e = idx - NX - 1536;
      int t = e >> 5, dh = e & 31;
      double invf = pow(10000.0, -(double)(dh >> 1) / 16.0);
      double ang = (double)t * invf;
      cosT[e] = (float)cos(ang);
      sinT[e] = (float)sin(ang);
    }
  } else {
    const int idx = blockIdx.x - 4358;     // [0,4096)
    const int z = idx >> 10;
    const int rem = idx & 1023;
    const int bx = rem & 31, by = rem >> 5;
    const float* src; u16* dst; int N; int roff;
    if (z == 0)      { src = wq; dst = wcat; N = 1024; roff = 0; }
    else if (z == 1) { src = wk; dst = wcat; N = 256;  roff = 1024; }
    else if (z == 2) { src = wv; dst = wcat; N = 256;  roff = 1280; }
    else             { src = wo; dst = wot;  N = 1024; roff = 0; }
    const int n0 = bx << 5;
    if (n0 >= N) return;
    const int k0 = by << 5;
    const int tx = threadIdx.x & 31, ty = threadIdx.x >> 5;
#pragma unroll
    for (int r = 0; r < 32; r += 8)
      tile[ty + r][tx] = src[(size_t)(k0 + ty + r) * N + n0 + tx];
    __syncthreads();
#pragma unroll
    for (int r = 0; r < 32; r += 8)
      dst[((size_t)(roff + n0 + ty + r) << 10) + k0 + tx] = f2bf(tile[tx][ty + r]);
  }
}

// ---------------- GEMM: C[M][N] = A[M][K] @ Bt[N][K]^T, tile 128x64 ----------------
// mode 0: block bx = one head: bx<16 Q, 16..19 K (x8-interleaved transpose), 20..23 V (transposed [d][t]).
// mode 1: bias epilogue -> f32 out.
__global__ __launch_bounds__(256) void gemm_kernel(
    const u16* __restrict__ A, const u16* __restrict__ Bt, int K, int mode,
    const float* __restrict__ bias_cat, u16* __restrict__ qbuf, u16* __restrict__ kbufT,
    u16* __restrict__ vbufT, const float* __restrict__ bo, float* __restrict__ outp,
    const float* __restrict__ cosT, const float* __restrict__ sinT,
    const float* __restrict__ hw)
{
  __shared__ alignas(16) char ldsA[16384];
  __shared__ alignas(16) char ldsB[8192];
  const int tid = threadIdx.x;
  const int lane = tid & 63, wid = tid >> 6;
  const int l15 = lane & 15, lg = lane >> 4;
  const int wm = wid << 5;
  const size_t K_ = (size_t)K;
  const u16* Apan = A + (size_t)blockIdx.y * 128 * K_;
  const u16* Bpan = Bt + (size_t)blockIdx.x * 64 * K_;

  f32x4 acc[2][4];
  const f32x4 fz = {0.f, 0.f, 0.f, 0.f};
#pragma unroll
  for (int mt = 0; mt < 2; ++mt)
#pragma unroll
    for (int nt = 0; nt < 4; ++nt) acc[mt][nt] = fz;

  for (int k0 = 0; k0 < K; k0 += 64) {
#pragma unroll
    for (int i = 0; i < 4; ++i) {
      const int grp = i * 4 + wid;            // wave-uniform group [0,16)
      const int c = grp * 64 + lane;
      const int r = c >> 3, k8 = (c & 7) << 3;
      const u16* ga = Apan + (size_t)r * K_ + k0 + k8;
      __builtin_amdgcn_global_load_lds((const GLB void*)ga, (LDS void*)(ldsA + grp * 1024), 16, 0, 0);
      if (i < 2) {
        const u16* gb = Bpan + (size_t)r * K_ + k0 + k8;
        __builtin_amdgcn_global_load_lds((const GLB void*)gb, (LDS void*)(ldsB + grp * 1024), 16, 0, 0);
      }
    }
    __syncthreads();
#pragma unroll
    for (int ks = 0; ks < 2; ++ks) {
      const int kbyte = ks * 64 + lg * 16;
      bf16x8 af[2], bfr[4];
#pragma unroll
      for (int mt = 0; mt < 2; ++mt)
        af[mt] = *(const bf16x8*)(ldsA + (wm + mt * 16 + l15) * 128 + kbyte);
#pragma unroll
      for (int nt = 0; nt < 4; ++nt)
        bfr[nt] = *(const bf16x8*)(ldsB + (nt * 16 + l15) * 128 + kbyte);
#pragma unroll
      for (int mt = 0; mt < 2; ++mt)
#pragma unroll
        for (int nt = 0; nt < 4; ++nt)
          acc[mt][nt] = __builtin_amdgcn_mfma_f32_16x16x32_bf16(af[mt], bfr[nt], acc[mt][nt], 0, 0, 0);
    }
    __syncthreads();
  }

  const int rb = blockIdx.y * 128 + wm + (lg << 2);
  const int bx = blockIdx.x;

  if (mode == 0) {
    const bool isQ = (bx < 16);
    const bool isV = (bx >= 20);
    const float hws = isQ ? hw[bx] * 0.125f : 1.0f;
    float bia[4];
#pragma unroll
    for (int nt = 0; nt < 4; ++nt) bia[nt] = bias_cat[bx * 64 + l15 + nt * 16];
    if (isV) {
#pragma unroll
      for (int mt = 0; mt < 2; ++mt) {
        const int r0 = rb + mt * 16;
        const int bb = r0 >> 11, t0 = r0 & 2047;
        const size_t base = ((size_t)(bb * 4 + (bx - 20))) << 17;
#pragma unroll
        for (int nt = 0; nt < 4; ++nt) {
          u16x4 pk;
#pragma unroll
          for (int j = 0; j < 4; ++j) pk[j] = f2bf(acc[mt][nt][j] + bia[nt]);
          const int d = l15 + nt * 16;
          *(u16x4*)(vbufT + base + (size_t)d * 2048 + t0) = pk;
        }
      }
    } else {
#pragma unroll
      for (int mt = 0; mt < 2; ++mt) {
#pragma unroll
        for (int j = 0; j < 4; ++j) {
          const int r = rb + mt * 16 + j;
          const int bb = r >> 11, t = r & 2047;
          float z[4];
#pragma unroll
          for (int nt = 0; nt < 4; ++nt) z[nt] = acc[mt][nt][j] + bia[nt];
          const float c0 = cosT[(t << 5) + l15],      s0 = sinT[(t << 5) + l15];
          const float c1 = cosT[(t << 5) + l15 + 16], s1 = sinT[(t << 5) + l15 + 16];
          const float n0 = (z[0] * c0 - z[2] * s0) * hws;
          const float n2 = (z[2] * c0 + z[0] * s0) * hws;
          const float n1 = (z[1] * c1 - z[3] * s1) * hws;
          const float n3 = (z[3] * c1 + z[1] * s1) * hws;
          z[0] = n0; z[1] = n1; z[2] = n2; z[3] = n3;
#pragma unroll
          for (int nt = 0; nt < 4; ++nt) {
            const int d = l15 + nt * 16;
            const u16 val = f2bf(z[nt]);
            if (isQ) {
              qbuf[(((size_t)(bb * 16 + bx) * 2048 + t) << 6) + d] = val;
            } else {
              kbufT[(((size_t)(bb * 4 + (bx - 16))) << 17) + ((d >> 3) << 14) + (t << 3) + (d & 7)] = val;
            }
          }
        }
      }
    }
  } else {
#pragma unroll
    for (int nt = 0; nt < 4; ++nt) {
      const int c = bx * 64 + l15 + nt * 16;
      const float bias = bo[c];
#pragma unroll
      for (int mt = 0; mt < 2; ++mt) {
#pragma unroll
        for (int j = 0; j < 4; ++j) {
          const int r = rb + mt * 16 + j;
          outp[(size_t)r * 1024 + c] = acc[mt][nt][j] + bias;
        }
      }
    }
  }
}

// ---------------- combined attention: band blocks [0,4096) + glob-partial blocks [4096,4608) ----
// Forced-ILP: K(8)+V(8)+Q0(8)+Q1(8) loads issued and pinned (32 in flight, one latency);
// Q2/Q3 reuse Q0/Q1 registers, issued under the dot compute.
__global__ __launch_bounds__(256, 3) void attn_comb_kernel(
    const u16* __restrict__ qbuf, const u16* __restrict__ kbufT,
    const u16* __restrict__ vbufT, u16* __restrict__ obuf,
    float* __restrict__ pm, float* __restrict__ pl, float* __restrict__ po)
{
  __shared__ alignas(16) u16 plds[4][16][64];
  const int tid = threadIdx.x;
  const int lane = tid & 63, w = tid >> 6;
  const int l15 = lane & 15, lg = lane >> 4;
  const f32x4 fz = {0.f, 0.f, 0.f, 0.f};
  u16* pw = (u16*)plds[w];

  const bool isBand = (blockIdx.x < 4096);
  int b, hkv, i, kc = 0, a = 0;
  if (isBand) {
    const int gw = blockIdx.x * 4 + w;       // [0, 16384)
    i = gw & 2047;
    hkv = (gw >> 11) & 3;
    b = gw >> 13;
    if (i < 8) return;
    a = (i - 12) & ~7;
  } else {
    const int u = (blockIdx.x - 4096) * 4 + w;   // [0,2048)
    kc = u & 31;
    const int yi = (u >> 5) & 31;
    b = u >> 10;
    hkv = yi & 3;
    i = yi >> 2;
  }

  const u16* KpT = kbufT + (((size_t)(b * 4 + hkv)) << 17);
  const u16* VpT = vbufT + (((size_t)(b * 4 + hkv)) << 17);
  const u16* Qr0 = qbuf + ((((size_t)(b * 16 + hkv * 4 + 0)) * 2048 + i) << 6);
  const u16* Qr1 = qbuf + ((((size_t)(b * 16 + hkv * 4 + 1)) * 2048 + i) << 6);
  const u16* Qr2 = qbuf + ((((size_t)(b * 16 + hkv * 4 + 2)) * 2048 + i) << 6);
  const u16* Qr3 = qbuf + ((((size_t)(b * 16 + hkv * 4 + 3)) * 2048 + i) << 6);

  // lane's key index
  int jc; bool act;
  if (isBand) {
    int j;
    if (lane < 8)       { j = lane; act = true; }
    else if (lane < 40) { j = a + lane - 8; act = (j >= 8) && (j < 2048) && (j >= i - 12) && (j <= i + 12); }
    else                { j = 0; act = false; }
    jc = j < 0 ? 0 : (j > 2047 ? 2047 : j);
  } else {
    jc = (kc << 6) + lane; act = true;
  }

  // ---- issue K, V, Q0, Q1 (32 loads in flight), then pin all ----
  u16x8 k8v[8], vfb[8], qA[8], qB[8];
#pragma unroll
  for (int d8 = 0; d8 < 8; ++d8)
    k8v[d8] = *(const u16x8*)(KpT + (d8 << 14) + (jc << 3));
#pragma unroll
  for (int db = 0; db < 4; ++db) {
#pragma unroll
    for (int ch = 0; ch < 2; ++ch) {
      const int sl0 = ch * 32 + lg * 8;
      int j0;
      if (isBand) {
        j0 = (sl0 < 8) ? 0 : a + sl0 - 8;
        j0 = j0 < 0 ? 0 : (j0 > 2040 ? 2040 : j0);
      } else {
        j0 = (kc << 6) + sl0;
      }
      vfb[db * 2 + ch] = *(const u16x8*)(VpT + (size_t)(db * 16 + l15) * 2048 + j0);
    }
  }
#pragma unroll
  for (int d8 = 0; d8 < 8; ++d8) qA[d8] = *(const u16x8*)(Qr0 + d8 * 8);
#pragma unroll
  for (int d8 = 0; d8 < 8; ++d8) qB[d8] = *(const u16x8*)(Qr1 + d8 * 8);
#pragma unroll
  for (int d8 = 0; d8 < 8; ++d8) { pinv(k8v[d8]); pinv(vfb[d8]); pinv(qA[d8]); pinv(qB[d8]); }

  float s0 = 0.f, s1 = 0.f, s2 = 0.f, s3 = 0.f;
#pragma unroll
  for (int d8 = 0; d8 < 8; ++d8) s0 = dot8(k8v[d8], qA[d8], s0);
  // issue Q2 into qA while s1 computes
#pragma unroll
  for (int d8 = 0; d8 < 8; ++d8) qA[d8] = *(const u16x8*)(Qr2 + d8 * 8);
#pragma unroll
  for (int d8 = 0; d8 < 8; ++d8) s1 = dot8(k8v[d8], qB[d8], s1);
  // issue Q3 into qB while s2 computes
#pragma unroll
  for (int d8 = 0; d8 < 8; ++d8) qB[d8] = *(const u16x8*)(Qr3 + d8 * 8);
#pragma unroll
  for (int d8 = 0; d8 < 8; ++d8) s2 = dot8(k8v[d8], qA[d8], s2);
#pragma unroll
  for (int d8 = 0; d8 < 8; ++d8) s3 = dot8(k8v[d8], qB[d8], s3);

  if (!act) { s0 = -1e30f; s1 = -1e30f; s2 = -1e30f; s3 = -1e30f; }

  float m0 = s0, m1 = s1, m2 = s2, m3 = s3;
#pragma unroll
  for (int sh = 32; sh >= 1; sh >>= 1) {
    m0 = fmaxf(m0, __shfl_xor(m0, sh));
    m1 = fmaxf(m1, __shfl_xor(m1, sh));
    m2 = fmaxf(m2, __shfl_xor(m2, sh));
    m3 = fmaxf(m3, __shfl_xor(m3, sh));
  }
  float p0 = act ? __expf(s0 - m0) : 0.f;
  float p1 = act ? __expf(s1 - m1) : 0.f;
  float p2 = act ? __expf(s2 - m2) : 0.f;
  float p3 = act ? __expf(s3 - m3) : 0.f;
  float l0 = p0, l1 = p1, l2 = p2, l3 = p3;
#pragma unroll
  for (int sh = 32; sh >= 1; sh >>= 1) {
    l0 += __shfl_xor(l0, sh);
    l1 += __shfl_xor(l1, sh);
    l2 += __shfl_xor(l2, sh);
    l3 += __shfl_xor(l3, sh);
  }

  // P (bf16) -> LDS, XOR-swizzled by row; band path normalizes here
  if (isBand) {
    pw[0 * 64 + (lane ^ 0)]  = f2bf(p0 / l0);
    pw[1 * 64 + (lane ^ 8)]  = f2bf(p1 / l1);
    pw[2 * 64 + (lane ^ 16)] = f2bf(p2 / l2);
    pw[3 * 64 + (lane ^ 24)] = f2bf(p3 / l3);
  } else {
    pw[0 * 64 + (lane ^ 0)]  = f2bf(p0);
    pw[1 * 64 + (lane ^ 8)]  = f2bf(p1);
    pw[2 * 64 + (lane ^ 16)] = f2bf(p2);
    pw[3 * 64 + (lane ^ 24)] = f2bf(p3);
  }

  bf16x8 paf[2];
#pragma unroll
  for (int ch = 0; ch < 2; ++ch)
    paf[ch] = *(const bf16x8*)(pw + l15 * 64 + ((ch * 32 + lg * 8) ^ ((l15 & 7) << 3)));

  f32x4 oacc[4];
#pragma unroll
  for (int db = 0; db < 4; ++db) oacc[db] = fz;
  __builtin_amdgcn_s_setprio(1);
#pragma unroll
  for (int db = 0; db < 4; ++db)
#pragma unroll
    for (int ch = 0; ch < 2; ++ch)
      oacc[db] = __builtin_amdgcn_mfma_f32_16x16x32_bf16(paf[ch], asbf(vfb[db * 2 + ch]), oacc[db], 0, 0, 0);
  __builtin_amdgcn_s_setprio(0);

  // C layout: row (=head) = lg*4 + reg, col = l15 -> heads live in lg==0 lanes
  if (isBand) {
    if (lg == 0) {
      const size_t rowo = ((size_t)(b * 2048 + i)) << 10;
      const int hb = hkv * 4;
#pragma unroll
      for (int db = 0; db < 4; ++db)
#pragma unroll
        for (int h = 0; h < 4; ++h)
          obuf[rowo + (hb + h) * 64 + db * 16 + l15] = f2bf(oacc[db][h]);
    }
  } else {
    const int part = (((b * 4 + hkv) * 8 + i) << 5) + kc;
    if (lane == 0) {
      pm[part * 4 + 0] = m0; pm[part * 4 + 1] = m1; pm[part * 4 + 2] = m2; pm[part * 4 + 3] = m3;
      pl[part * 4 + 0] = l0; pl[part * 4 + 1] = l1; pl[part * 4 + 2] = l2; pl[part * 4 + 3] = l3;
    }
    if (lg == 0) {
      float* pob = po + (((size_t)part << 2) << 6);
#pragma unroll
      for (int db = 0; db < 4; ++db)
#pragma unroll
        for (int h = 0; h < 4; ++h)
          pob[h * 64 + db * 16 + l15] = oacc[db][h];
    }
  }
}

// ---------------- global rows i<8, phase 2: merge 32 partials per (row, head) ----------
__global__ __launch_bounds__(256) void attn_globm_kernel(
    const float* __restrict__ pm, const float* __restrict__ pl,
    const float* __restrict__ po, u16* __restrict__ obuf)
{
  const int idx = blockIdx.x;   // [0,64): (b,hkv,i)
  const int i = idx & 7;
  const int hkv = (idx >> 3) & 3;
  const int b = idx >> 5;
  const int tid = threadIdx.x;
  const int lane = tid & 63, h = tid >> 6;
  const int base = ((b * 4 + hkv) * 8 + i) << 5;

  float M = -1e30f;
#pragma unroll 8
  for (int kc = 0; kc < 32; ++kc) M = fmaxf(M, pm[(base + kc) * 4 + h]);
  float L = 0.f, O = 0.f;
#pragma unroll 8
  for (int kc = 0; kc < 32; ++kc) {
    float sc = __expf(pm[(base + kc) * 4 + h] - M);
    L += pl[(base + kc) * 4 + h] * sc;
    O = fmaf(po[((((size_t)(base + kc) << 2) + h) << 6) + lane], sc, O);
  }
  obuf[(((size_t)(b * 2048 + i)) << 10) + (hkv * 4 + h) * 64 + lane] = f2bf(O / L);
}

extern "C" void kernel_launch(void* const* d_in, const int* in_sizes, int n_in,
                              void* d_out, int out_size, void* d_ws, size_t ws_size,
                              hipStream_t stream) {
  const float* x  = (const float*)d_in[0];
  const float* Wq = (const float*)d_in[1];
  const float* bq = (const float*)d_in[2];
  const float* Wk = (const float*)d_in[3];
  const float* bk = (const float*)d_in[4];
  const float* Wv = (const float*)d_in[5];
  const float* bv = (const float*)d_in[6];
  const float* Wo = (const float*)d_in[7];
  const float* bo = (const float*)d_in[8];
  const float* hw = (const float*)d_in[9];
  float* out = (float*)d_out;

  char* ws = (char*)d_ws;
  size_t off = 0;
  auto alloc = [&](size_t bytes) { char* p = ws + off; off += (bytes + 255) & ~(size_t)255; return p; };
  u16* xbf    = (u16*)alloc((size_t)4096 * 1024 * 2);   // also reused as obuf
  u16* wcat   = (u16*)alloc((size_t)1536 * 1024 * 2);
  u16* wot    = (u16*)alloc((size_t)1024 * 1024 * 2);
  float* biascat = (float*)alloc(1536 * 4);
  float* cosT = (float*)alloc(65536 * 4);
  float* sinT = (float*)alloc(65536 * 4);
  u16* qbuf   = (u16*)alloc((size_t)2 * 16 * 2048 * 64 * 2);
  u16* kbufT  = (u16*)alloc((size_t)2 * 4 * 2048 * 64 * 2);
  u16* vbufT  = (u16*)alloc((size_t)2 * 4 * 2048 * 64 * 2);
  float* pm   = (float*)alloc((size_t)2048 * 4 * 4);
  float* pl   = (float*)alloc((size_t)2048 * 4 * 4);
  float* po   = (float*)alloc((size_t)2048 * 4 * 64 * 4);
  u16* obuf   = xbf;  // xbf dead after first GEMM

  prepw_kernel<<<8454, 256, 0, stream>>>(x, bq, bk, bv, biascat, cosT, sinT, xbf,
                                         Wq, Wk, Wv, Wo, wcat, wot);
  gemm_kernel<<<dim3(24, 32), 256, 0, stream>>>(xbf, wcat, 1024, 0, biascat, qbuf, kbufT, vbufT,
                                                nullptr, nullptr, cosT, sinT, hw);
  attn_comb_kernel<<<4608, 256, 0, stream>>>(qbuf, kbufT, vbufT, obuf, pm, pl, po);
  attn_globm_kernel<<<64, 256, 0, stream>>>(pm, pl, po, obuf);
  gemm_kernel<<<dim3(16, 32), 256, 0, stream>>>(obuf, wot, 1024, 1, nullptr, nullptr, nullptr,
                                               nullptr, bo, out, nullptr, nullptr, nullptr);
}

// Round 23
// 86.926 us; speedup vs baseline: 1.3124x; 1.3124x over previous
//
#include <hip/hip_runtime.h>
#include <hip/hip_bf16.h>
#include <math.h>

typedef short bf16x8 __attribute__((ext_vector_type(8)));
typedef float f32x4 __attribute__((ext_vector_type(4)));
typedef unsigned short u16;
typedef u16 u16x4 __attribute__((ext_vector_type(4)));
typedef u16 u16x8 __attribute__((ext_vector_type(8)));

#define DEV static __device__ __forceinline__
#define GLB __attribute__((address_space(1)))
#define LDS __attribute__((address_space(3)))

#if defined(__has_builtin)
#if __has_builtin(__builtin_amdgcn_fdot2_f32_bf16)
#define HAS_BF16_DOT2 1
#endif
#endif

#ifdef HAS_BF16_DOT2
typedef __bf16 bf16x2 __attribute__((ext_vector_type(2)));
#endif

DEV float bf2f(u16 u) { union { unsigned int i; float f; } v; v.i = ((unsigned int)u) << 16; return v.f; }
DEV u16 f2bf(float f) {
  union { float fl; unsigned int i; } v; v.fl = f;
  return (u16)((v.i + 0x7FFFu + ((v.i >> 16) & 1u)) >> 16);
}

// 8-element bf16 dot: acc += sum_e k[e]*q[e]
DEV float dot8(u16x8 k, u16x8 q, float acc) {
#ifdef HAS_BF16_DOT2
  union { u16x8 u; bf16x2 b[4]; } ku, qu;
  ku.u = k; qu.u = q;
#pragma unroll
  for (int e = 0; e < 4; ++e)
    acc = __builtin_amdgcn_fdot2_f32_bf16(ku.b[e], qu.b[e], acc, false);
#else
#pragma unroll
  for (int e = 0; e < 8; ++e) acc = fmaf(bf2f(k[e]), bf2f(q[e]), acc);
#endif
  return acc;
}

// ---------------- prep (blocks 0..4357) + weight transpose (blocks 4358..8453) ----------------
__global__ __launch_bounds__(256) void prepw_kernel(
    const float* __restrict__ x, const float* __restrict__ bq,
    const float* __restrict__ bk, const float* __restrict__ bv,
    float* __restrict__ biascat, float* __restrict__ cosT, float* __restrict__ sinT,
    u16* __restrict__ xbf,
    const float* __restrict__ wq, const float* __restrict__ wk,
    const float* __restrict__ wv, const float* __restrict__ wo,
    u16* __restrict__ wcat, u16* __restrict__ wot)
{
  __shared__ float tile[32][33];
  if (blockIdx.x < 4358) {
    int idx = blockIdx.x * 256 + threadIdx.x;
    const int NX = (4096 * 1024) / 4;
    if (idx < NX) {
      const float4 v = ((const float4*)x)[idx];
      u16x4 o;
      o[0] = f2bf(v.x); o[1] = f2bf(v.y); o[2] = f2bf(v.z); o[3] = f2bf(v.w);
      *((u16x4*)xbf + idx) = o;
    } else if (idx < NX + 1536) {
      int n = idx - NX;
      biascat[n] = (n < 1024) ? bq[n] : (n < 1280 ? bk[n - 1024] : bv[n - 1280]);
    } else if (idx < NX + 1536 + 65536) {
      int e = idx - NX - 1536;
      int t = e >> 5, dh = e & 31;
      double invf = pow(10000.0, -(double)(dh >> 1) / 16.0);
      double ang = (double)t * invf;
      cosT[e] = (float)cos(ang);
      sinT[e] = (float)sin(ang);
    }
  } else {
    const int idx = blockIdx.x - 4358;     // [0,4096)
    const int z = idx >> 10;
    const int rem = idx & 1023;
    const int bx = rem & 31, by = rem >> 5;
    const float* src; u16* dst; int N; int roff;
    if (z == 0)      { src = wq; dst = wcat; N = 1024; roff = 0; }
    else if (z == 1) { src = wk; dst = wcat; N = 256;  roff = 1024; }
    else if (z == 2) { src = wv; dst = wcat; N = 256;  roff = 1280; }
    else             { src = wo; dst = wot;  N = 1024; roff = 0; }
    const int n0 = bx << 5;
    if (n0 >= N) return;
    const int k0 = by << 5;
    const int tx = threadIdx.x & 31, ty = threadIdx.x >> 5;
#pragma unroll
    for (int r = 0; r < 32; r += 8)
      tile[ty + r][tx] = src[(size_t)(k0 + ty + r) * N + n0 + tx];
    __syncthreads();
#pragma unroll
    for (int r = 0; r < 32; r += 8)
      dst[((size_t)(roff + n0 + ty + r) << 10) + k0 + tx] = f2bf(tile[tx][ty + r]);
  }
}

// ---------------- GEMM: C[M][N] = A[M][K] @ Bt[N][K]^T, tile 128x64 ----------------
// mode 0: block bx = one head: bx<16 Q, 16..19 K (x8-interleaved transpose), 20..23 V (transposed [d][t]).
// mode 1: bias epilogue -> f32 out.
__global__ __launch_bounds__(256) void gemm_kernel(
    const u16* __restrict__ A, const u16* __restrict__ Bt, int K, int mode,
    const float* __restrict__ bias_cat, u16* __restrict__ qbuf, u16* __restrict__ kbufT,
    u16* __restrict__ vbufT, const float* __restrict__ bo, float* __restrict__ outp,
    const float* __restrict__ cosT, const float* __restrict__ sinT,
    const float* __restrict__ hw)
{
  __shared__ alignas(16) char ldsA[16384];
  __shared__ alignas(16) char ldsB[8192];
  const int tid = threadIdx.x;
  const int lane = tid & 63, wid = tid >> 6;
  const int l15 = lane & 15, lg = lane >> 4;
  const int wm = wid << 5;
  const size_t K_ = (size_t)K;
  const u16* Apan = A + (size_t)blockIdx.y * 128 * K_;
  const u16* Bpan = Bt + (size_t)blockIdx.x * 64 * K_;

  f32x4 acc[2][4];
  const f32x4 fz = {0.f, 0.f, 0.f, 0.f};
#pragma unroll
  for (int mt = 0; mt < 2; ++mt)
#pragma unroll
    for (int nt = 0; nt < 4; ++nt) acc[mt][nt] = fz;

  for (int k0 = 0; k0 < K; k0 += 64) {
#pragma unroll
    for (int i = 0; i < 4; ++i) {
      const int grp = i * 4 + wid;            // wave-uniform group [0,16)
      const int c = grp * 64 + lane;
      const int r = c >> 3, k8 = (c & 7) << 3;
      const u16* ga = Apan + (size_t)r * K_ + k0 + k8;
      __builtin_amdgcn_global_load_lds((const GLB void*)ga, (LDS void*)(ldsA + grp * 1024), 16, 0, 0);
      if (i < 2) {
        const u16* gb = Bpan + (size_t)r * K_ + k0 + k8;
        __builtin_amdgcn_global_load_lds((const GLB void*)gb, (LDS void*)(ldsB + grp * 1024), 16, 0, 0);
      }
    }
    __syncthreads();
#pragma unroll
    for (int ks = 0; ks < 2; ++ks) {
      const int kbyte = ks * 64 + lg * 16;
      bf16x8 af[2], bfr[4];
#pragma unroll
      for (int mt = 0; mt < 2; ++mt)
        af[mt] = *(const bf16x8*)(ldsA + (wm + mt * 16 + l15) * 128 + kbyte);
#pragma unroll
      for (int nt = 0; nt < 4; ++nt)
        bfr[nt] = *(const bf16x8*)(ldsB + (nt * 16 + l15) * 128 + kbyte);
#pragma unroll
      for (int mt = 0; mt < 2; ++mt)
#pragma unroll
        for (int nt = 0; nt < 4; ++nt)
          acc[mt][nt] = __builtin_amdgcn_mfma_f32_16x16x32_bf16(af[mt], bfr[nt], acc[mt][nt], 0, 0, 0);
    }
    __syncthreads();
  }

  const int rb = blockIdx.y * 128 + wm + (lg << 2);
  const int bx = blockIdx.x;

  if (mode == 0) {
    const bool isQ = (bx < 16);
    const bool isV = (bx >= 20);
    const float hws = isQ ? hw[bx] * 0.125f : 1.0f;
    float bia[4];
#pragma unroll
    for (int nt = 0; nt < 4; ++nt) bia[nt] = bias_cat[bx * 64 + l15 + nt * 16];
    if (isV) {
#pragma unroll
      for (int mt = 0; mt < 2; ++mt) {
        const int r0 = rb + mt * 16;
        const int bb = r0 >> 11, t0 = r0 & 2047;
        const size_t base = ((size_t)(bb * 4 + (bx - 20))) << 17;
#pragma unroll
        for (int nt = 0; nt < 4; ++nt) {
          u16x4 pk;
#pragma unroll
          for (int j = 0; j < 4; ++j) pk[j] = f2bf(acc[mt][nt][j] + bia[nt]);
          const int d = l15 + nt * 16;
          *(u16x4*)(vbufT + base + (size_t)d * 2048 + t0) = pk;
        }
      }
    } else {
#pragma unroll
      for (int mt = 0; mt < 2; ++mt) {
#pragma unroll
        for (int j = 0; j < 4; ++j) {
          const int r = rb + mt * 16 + j;
          const int bb = r >> 11, t = r & 2047;
          float z[4];
#pragma unroll
          for (int nt = 0; nt < 4; ++nt) z[nt] = acc[mt][nt][j] + bia[nt];
          const float c0 = cosT[(t << 5) + l15],      s0 = sinT[(t << 5) + l15];
          const float c1 = cosT[(t << 5) + l15 + 16], s1 = sinT[(t << 5) + l15 + 16];
          const float n0 = (z[0] * c0 - z[2] * s0) * hws;
          const float n2 = (z[2] * c0 + z[0] * s0) * hws;
          const float n1 = (z[1] * c1 - z[3] * s1) * hws;
          const float n3 = (z[3] * c1 + z[1] * s1) * hws;
          z[0] = n0; z[1] = n1; z[2] = n2; z[3] = n3;
#pragma unroll
          for (int nt = 0; nt < 4; ++nt) {
            const int d = l15 + nt * 16;
            const u16 val = f2bf(z[nt]);
            if (isQ) {
              qbuf[(((size_t)(bb * 16 + bx) * 2048 + t) << 6) + d] = val;
            } else {
              kbufT[(((size_t)(bb * 4 + (bx - 16))) << 17) + ((d >> 3) << 14) + (t << 3) + (d & 7)] = val;
            }
          }
        }
      }
    }
  } else {
#pragma unroll
    for (int nt = 0; nt < 4; ++nt) {
      const int c = bx * 64 + l15 + nt * 16;
      const float bias = bo[c];
#pragma unroll
      for (int mt = 0; mt < 2; ++mt) {
#pragma unroll
        for (int j = 0; j < 4; ++j) {
          const int r = rb + mt * 16 + j;
          outp[(size_t)r * 1024 + c] = acc[mt][nt][j] + bias;
        }
      }
    }
  }
}

// ---------------- banded rows: one wave = 16 rows x 1 head, full-MFMA QK^T + PV ----------------
// Rows i0..i0+15, i0 = 8 + 16k. Slots: t<8 -> j=t; t>=8 -> j = a+t-8, a=(i0-12)&~7 = i0-16.
// Window slots cover [i0-16, i0+39] superset of needed [i0-12, i0+27]; inactive slots get P=0.
__global__ __launch_bounds__(256) void attn_band_kernel(
    const u16* __restrict__ qbuf, const u16* __restrict__ kbufT,
    const u16* __restrict__ vbufT, u16* __restrict__ obuf)
{
  __shared__ alignas(16) u16 plds[4][16][64];
  const int tid = threadIdx.x;
  const int lane = tid & 63, w = tid >> 6;
  const int l15 = lane & 15, lg = lane >> 4;
  const f32x4 fz = {0.f, 0.f, 0.f, 0.f};
  u16* pw = (u16*)plds[w];

  const int gw = blockIdx.x * 4 + w;   // [0, 4096): (b, h, k)
  const int k = gw & 127;
  const int h = (gw >> 7) & 15;
  const int b = gw >> 11;
  const int i0 = 8 + k * 16;
  const int a = i0 - 16;
  const int hkv = h >> 2;

  const u16* KpT = kbufT + (((size_t)(b * 4 + hkv)) << 17);
  const u16* VpT = vbufT + (((size_t)(b * 4 + hkv)) << 17);
  const u16* Qp  = qbuf + (((size_t)(b * 16 + h)) << 17);   // [t][d]

  // ---- QK^T: S[16 q][64 slots] ----
  // A (Q): lane l15 = q-row (i0+l15), k-octet = ch*32+lg*8 (same mapping as verified GEMM af)
  bf16x8 qa[2];
#pragma unroll
  for (int ch = 0; ch < 2; ++ch)
    qa[ch] = *(const bf16x8*)(Qp + (size_t)(i0 + l15) * 64 + ch * 32 + lg * 8);

  // B (K): lane l15 = slot col (mt*16+l15), k-octet d8 = ch*4+lg (verified kbufT octet pattern)
  int slotj[4];
#pragma unroll
  for (int mt = 0; mt < 4; ++mt) {
    const int t = mt * 16 + l15;
    int j = (t < 8) ? t : a + t - 8;
    slotj[mt] = j < 0 ? 0 : (j > 2047 ? 2047 : j);
  }

  f32x4 s[4];
#pragma unroll
  for (int mt = 0; mt < 4; ++mt) s[mt] = fz;
#pragma unroll
  for (int ch = 0; ch < 2; ++ch) {
#pragma unroll
    for (int mt = 0; mt < 4; ++mt) {
      bf16x8 kf = *(const bf16x8*)(KpT + ((size_t)(ch * 4 + lg) << 14) + (slotj[mt] << 3));
      s[mt] = __builtin_amdgcn_mfma_f32_16x16x32_bf16(qa[ch], kf, s[mt], 0, 0, 0);
    }
  }

  // ---- mask + softmax per q-row (q = lg*4+jr, slots across mt regs + l15 lanes) ----
#pragma unroll
  for (int mt = 0; mt < 4; ++mt) {
    const int t = mt * 16 + l15;
    const int j = (t < 8) ? t : a + t - 8;
#pragma unroll
    for (int jr = 0; jr < 4; ++jr) {
      const int i = i0 + lg * 4 + jr;
      bool ok;
      if (t < 8) ok = true;
      else ok = (j >= 8) && (j < 2048) && (j >= i - 12) && (j <= i + 12);
      if (!ok) s[mt][jr] = -1e30f;
    }
  }
  float pinvl[4];
#pragma unroll
  for (int jr = 0; jr < 4; ++jr) {
    float m = fmaxf(fmaxf(s[0][jr], s[1][jr]), fmaxf(s[2][jr], s[3][jr]));
#pragma unroll
    for (int sh = 1; sh <= 8; sh <<= 1) m = fmaxf(m, __shfl_xor(m, sh));
    float sum = 0.f;
#pragma unroll
    for (int mt = 0; mt < 4; ++mt) {
      const float p = __expf(s[mt][jr] - m);
      s[mt][jr] = p;
      sum += p;
    }
#pragma unroll
    for (int sh = 1; sh <= 8; sh <<= 1) sum += __shfl_xor(sum, sh);
    pinvl[jr] = 1.f / sum;
  }

  // ---- normalized P -> LDS (row-XOR swizzle, octet granularity; verified R17 pattern) ----
#pragma unroll
  for (int mt = 0; mt < 4; ++mt) {
    const int t = mt * 16 + l15;
#pragma unroll
    for (int jr = 0; jr < 4; ++jr) {
      const int q = lg * 4 + jr;
      pw[q * 64 + (t ^ ((q & 7) << 3))] = f2bf(s[mt][jr] * pinvl[jr]);
    }
  }

  bf16x8 paf[2];
#pragma unroll
  for (int ch = 0; ch < 2; ++ch)
    paf[ch] = *(const bf16x8*)(pw + l15 * 64 + ((ch * 32 + lg * 8) ^ ((l15 & 7) << 3)));

  // ---- PV: O[16 q][64 d] (verified R17 pattern) ----
  f32x4 oacc[4];
#pragma unroll
  for (int db = 0; db < 4; ++db) oacc[db] = fz;
  __builtin_amdgcn_s_setprio(1);
#pragma unroll
  for (int db = 0; db < 4; ++db) {
#pragma unroll
    for (int ch = 0; ch < 2; ++ch) {
      const int sl0 = ch * 32 + lg * 8;
      int j0 = (sl0 < 8) ? 0 : a + sl0 - 8;
      j0 = j0 < 0 ? 0 : (j0 > 2040 ? 2040 : j0);
      bf16x8 vf = *(const bf16x8*)(VpT + (size_t)(db * 16 + l15) * 2048 + j0);
      oacc[db] = __builtin_amdgcn_mfma_f32_16x16x32_bf16(paf[ch], vf, oacc[db], 0, 0, 0);
    }
  }
  __builtin_amdgcn_s_setprio(0);

  // C layout: row(q) = lg*4+jr, col(d) = db*16+l15
#pragma unroll
  for (int jr = 0; jr < 4; ++jr) {
    const int i = i0 + lg * 4 + jr;
    if (i < 2048) {
      const size_t rowo = ((size_t)(b * 2048 + i)) << 10;
#pragma unroll
      for (int db = 0; db < 4; ++db)
        obuf[rowo + h * 64 + db * 16 + l15] = f2bf(oacc[db][jr]);
    }
  }
}

// ---------------- global rows i<8, phase 1: partial softmax over a 64-key chunk; MFMA PV ----
__global__ __launch_bounds__(64) void attn_globp_kernel(
    const u16* __restrict__ qbuf, const u16* __restrict__ kbufT,
    const u16* __restrict__ vbufT,
    float* __restrict__ pm, float* __restrict__ pl, float* __restrict__ po)
{
  __shared__ alignas(16) u16 plds[16][64];
  const int kc = blockIdx.x;
  const int hkv = blockIdx.y & 3;
  const int i = blockIdx.y >> 2;
  const int b = blockIdx.z;
  const int lane = threadIdx.x;
  const u16* KpT = kbufT + (((size_t)(b * 4 + hkv)) << 17);
  const u16* VpT = vbufT + (((size_t)(b * 4 + hkv)) << 17);
  const u16* Qr0 = qbuf + ((((size_t)(b * 16 + hkv * 4 + 0)) * 2048 + i) << 6);
  const u16* Qr1 = qbuf + ((((size_t)(b * 16 + hkv * 4 + 1)) * 2048 + i) << 6);
  const u16* Qr2 = qbuf + ((((size_t)(b * 16 + hkv * 4 + 2)) * 2048 + i) << 6);
  const u16* Qr3 = qbuf + ((((size_t)(b * 16 + hkv * 4 + 3)) * 2048 + i) << 6);

  const int j = (kc << 6) + lane;
  float s0 = 0.f, s1 = 0.f, s2 = 0.f, s3 = 0.f;
#pragma unroll
  for (int d8 = 0; d8 < 8; ++d8) {
    u16x8 k8 = *(const u16x8*)(KpT + (d8 << 14) + (j << 3));
    u16x8 q0 = *(const u16x8*)(Qr0 + d8 * 8);
    u16x8 q1 = *(const u16x8*)(Qr1 + d8 * 8);
    u16x8 q2 = *(const u16x8*)(Qr2 + d8 * 8);
    u16x8 q3 = *(const u16x8*)(Qr3 + d8 * 8);
    s0 = dot8(k8, q0, s0);
    s1 = dot8(k8, q1, s1);
    s2 = dot8(k8, q2, s2);
    s3 = dot8(k8, q3, s3);
  }
  float m0 = s0, m1 = s1, m2 = s2, m3 = s3;
#pragma unroll
  for (int sh = 32; sh >= 1; sh >>= 1) {
    m0 = fmaxf(m0, __shfl_xor(m0, sh));
    m1 = fmaxf(m1, __shfl_xor(m1, sh));
    m2 = fmaxf(m2, __shfl_xor(m2, sh));
    m3 = fmaxf(m3, __shfl_xor(m3, sh));
  }
  float p0 = __expf(s0 - m0), p1 = __expf(s1 - m1), p2 = __expf(s2 - m2), p3 = __expf(s3 - m3);
  float l0 = p0, l1 = p1, l2 = p2, l3 = p3;
#pragma unroll
  for (int sh = 32; sh >= 1; sh >>= 1) {
    l0 += __shfl_xor(l0, sh);
    l1 += __shfl_xor(l1, sh);
    l2 += __shfl_xor(l2, sh);
    l3 += __shfl_xor(l3, sh);
  }

  u16* pw = (u16*)plds;
  pw[0 * 64 + (lane ^ 0)]  = f2bf(p0);
  pw[1 * 64 + (lane ^ 8)]  = f2bf(p1);
  pw[2 * 64 + (lane ^ 16)] = f2bf(p2);
  pw[3 * 64 + (lane ^ 24)] = f2bf(p3);

  const int l15 = lane & 15, lg = lane >> 4;
  bf16x8 paf[2];
#pragma unroll
  for (int ch = 0; ch < 2; ++ch)
    paf[ch] = *(const bf16x8*)(pw + l15 * 64 + ((ch * 32 + lg * 8) ^ ((l15 & 7) << 3)));

  f32x4 oacc[4];
  const f32x4 fz = {0.f, 0.f, 0.f, 0.f};
#pragma unroll
  for (int db = 0; db < 4; ++db) oacc[db] = fz;
#pragma unroll
  for (int db = 0; db < 4; ++db) {
#pragma unroll
    for (int ch = 0; ch < 2; ++ch) {
      const int j0 = (kc << 6) + ch * 32 + lg * 8;
      bf16x8 vf = *(const bf16x8*)(VpT + (size_t)(db * 16 + l15) * 2048 + j0);
      oacc[db] = __builtin_amdgcn_mfma_f32_16x16x32_bf16(paf[ch], vf, oacc[db], 0, 0, 0);
    }
  }

  const int part = (((b * 4 + hkv) * 8 + i) << 5) + kc;
  if (lane == 0) {
    pm[part * 4 + 0] = m0; pm[part * 4 + 1] = m1; pm[part * 4 + 2] = m2; pm[part * 4 + 3] = m3;
    pl[part * 4 + 0] = l0; pl[part * 4 + 1] = l1; pl[part * 4 + 2] = l2; pl[part * 4 + 3] = l3;
  }
  if (lg == 0) {
    float* pob = po + (((size_t)part << 2) << 6);
#pragma unroll
    for (int db = 0; db < 4; ++db)
#pragma unroll
      for (int h = 0; h < 4; ++h)
        pob[h * 64 + db * 16 + l15] = oacc[db][h];
  }
}

// ---------------- global rows i<8, phase 2: merge 32 partials per (row, head) ----------
__global__ __launch_bounds__(256) void attn_globm_kernel(
    const float* __restrict__ pm, const float* __restrict__ pl,
    const float* __restrict__ po, u16* __restrict__ obuf)
{
  const int idx = blockIdx.x;   // [0,64): (b,hkv,i)
  const int i = idx & 7;
  const int hkv = (idx >> 3) & 3;
  const int b = idx >> 5;
  const int tid = threadIdx.x;
  const int lane = tid & 63, h = tid >> 6;
  const int base = ((b * 4 + hkv) * 8 + i) << 5;

  float M = -1e30f;
#pragma unroll 8
  for (int kc = 0; kc < 32; ++kc) M = fmaxf(M, pm[(base + kc) * 4 + h]);
  float L = 0.f, O = 0.f;
#pragma unroll 8
  for (int kc = 0; kc < 32; ++kc) {
    float sc = __expf(pm[(base + kc) * 4 + h] - M);
    L += pl[(base + kc) * 4 + h] * sc;
    O = fmaf(po[((((size_t)(base + kc) << 2) + h) << 6) + lane], sc, O);
  }
  obuf[(((size_t)(b * 2048 + i)) << 10) + (hkv * 4 + h) * 64 + lane] = f2bf(O / L);
}

extern "C" void kernel_launch(void* const* d_in, const int* in_sizes, int n_in,
                              void* d_out, int out_size, void* d_ws, size_t ws_size,
                              hipStream_t stream) {
  const float* x  = (const float*)d_in[0];
  const float* Wq = (const float*)d_in[1];
  const float* bq = (const float*)d_in[2];
  const float* Wk = (const float*)d_in[3];
  const float* bk = (const float*)d_in[4];
  const float* Wv = (const float*)d_in[5];
  const float* bv = (const float*)d_in[6];
  const float* Wo = (const float*)d_in[7];
  const float* bo = (const float*)d_in[8];
  const float* hw = (const float*)d_in[9];
  float* out = (float*)d_out;

  char* ws = (char*)d_ws;
  size_t off = 0;
  auto alloc = [&](size_t bytes) { char* p = ws + off; off += (bytes + 255) & ~(size_t)255; return p; };
  u16* xbf    = (u16*)alloc((size_t)4096 * 1024 * 2);   // also reused as obuf
  u16* wcat   = (u16*)alloc((size_t)1536 * 1024 * 2);
  u16* wot    = (u16*)alloc((size_t)1024 * 1024 * 2);
  float* biascat = (float*)alloc(1536 * 4);
  float* cosT = (float*)alloc(65536 * 4);
  float* sinT = (float*)alloc(65536 * 4);
  u16* qbuf   = (u16*)alloc((size_t)2 * 16 * 2048 * 64 * 2);
  u16* kbufT  = (u16*)alloc((size_t)2 * 4 * 2048 * 64 * 2);
  u16* vbufT  = (u16*)alloc((size_t)2 * 4 * 2048 * 64 * 2);
  float* pm   = (float*)alloc((size_t)2048 * 4 * 4);
  float* pl   = (float*)alloc((size_t)2048 * 4 * 4);
  float* po   = (float*)alloc((size_t)2048 * 4 * 64 * 4);
  u16* obuf   = xbf;  // xbf dead after first GEMM

  prepw_kernel<<<8454, 256, 0, stream>>>(x, bq, bk, bv, biascat, cosT, sinT, xbf,
                                         Wq, Wk, Wv, Wo, wcat, wot);
  gemm_kernel<<<dim3(24, 32), 256, 0, stream>>>(xbf, wcat, 1024, 0, biascat, qbuf, kbufT, vbufT,
                                                nullptr, nullptr, cosT, sinT, hw);
  attn_band_kernel<<<1024, 256, 0, stream>>>(qbuf, kbufT, vbufT, obuf);
  attn_globp_kernel<<<dim3(32, 32, 2), 64, 0, stream>>>(qbuf, kbufT, vbufT, pm, pl, po);
  attn_globm_kernel<<<64, 256, 0, stream>>>(pm, pl, po, obuf);
  gemm_kernel<<<dim3(16, 32), 256, 0, stream>>>(obuf, wot, 1024, 1, nullptr, nullptr, nullptr,
                                               nullptr, bo, out, nullptr, nullptr, nullptr);
}

// Round 24
// 85.317 us; speedup vs baseline: 1.3371x; 1.0189x over previous
//
#include <hip/hip_runtime.h>
#include <hip/hip_bf16.h>
#include <math.h>

typedef short bf16x8 __attribute__((ext_vector_type(8)));
typedef float f32x4 __attribute__((ext_vector_type(4)));
typedef unsigned short u16;
typedef u16 u16x4 __attribute__((ext_vector_type(4)));
typedef u16 u16x8 __attribute__((ext_vector_type(8)));

#define DEV static __device__ __forceinline__
#define GLB __attribute__((address_space(1)))
#define LDS __attribute__((address_space(3)))

#if defined(__has_builtin)
#if __has_builtin(__builtin_amdgcn_fdot2_f32_bf16)
#define HAS_BF16_DOT2 1
#endif
#endif

#ifdef HAS_BF16_DOT2
typedef __bf16 bf16x2 __attribute__((ext_vector_type(2)));
#endif

DEV float bf2f(u16 u) { union { unsigned int i; float f; } v; v.i = ((unsigned int)u) << 16; return v.f; }
DEV u16 f2bf(float f) {
  union { float fl; unsigned int i; } v; v.fl = f;
  return (u16)((v.i + 0x7FFFu + ((v.i >> 16) & 1u)) >> 16);
}

// 8-element bf16 dot: acc += sum_e k[e]*q[e]
DEV float dot8(u16x8 k, u16x8 q, float acc) {
#ifdef HAS_BF16_DOT2
  union { u16x8 u; bf16x2 b[4]; } ku, qu;
  ku.u = k; qu.u = q;
#pragma unroll
  for (int e = 0; e < 4; ++e)
    acc = __builtin_amdgcn_fdot2_f32_bf16(ku.b[e], qu.b[e], acc, false);
#else
#pragma unroll
  for (int e = 0; e < 8; ++e) acc = fmaf(bf2f(k[e]), bf2f(q[e]), acc);
#endif
  return acc;
}

// ---------------- prep (blocks 0..4357) + weight transpose (blocks 4358..8453) ----------------
__global__ __launch_bounds__(256) void prepw_kernel(
    const float* __restrict__ x, const float* __restrict__ bq,
    const float* __restrict__ bk, const float* __restrict__ bv,
    float* __restrict__ biascat, float* __restrict__ cosT, float* __restrict__ sinT,
    u16* __restrict__ xbf,
    const float* __restrict__ wq, const float* __restrict__ wk,
    const float* __restrict__ wv, const float* __restrict__ wo,
    u16* __restrict__ wcat, u16* __restrict__ wot)
{
  __shared__ float tile[32][33];
  if (blockIdx.x < 4358) {
    int idx = blockIdx.x * 256 + threadIdx.x;
    const int NX = (4096 * 1024) / 4;
    if (idx < NX) {
      const float4 v = ((const float4*)x)[idx];
      u16x4 o;
      o[0] = f2bf(v.x); o[1] = f2bf(v.y); o[2] = f2bf(v.z); o[3] = f2bf(v.w);
      *((u16x4*)xbf + idx) = o;
    } else if (idx < NX + 1536) {
      int n = idx - NX;
      biascat[n] = (n < 1024) ? bq[n] : (n < 1280 ? bk[n - 1024] : bv[n - 1280]);
    } else if (idx < NX + 1536 + 65536) {
      int e = idx - NX - 1536;
      int t = e >> 5, dh = e & 31;
      double invf = pow(10000.0, -(double)(dh >> 1) / 16.0);
      double ang = (double)t * invf;
      cosT[e] = (float)cos(ang);
      sinT[e] = (float)sin(ang);
    }
  } else {
    const int idx = blockIdx.x - 4358;     // [0,4096)
    const int z = idx >> 10;
    const int rem = idx & 1023;
    const int bx = rem & 31, by = rem >> 5;
    const float* src; u16* dst; int N; int roff;
    if (z == 0)      { src = wq; dst = wcat; N = 1024; roff = 0; }
    else if (z == 1) { src = wk; dst = wcat; N = 256;  roff = 1024; }
    else if (z == 2) { src = wv; dst = wcat; N = 256;  roff = 1280; }
    else             { src = wo; dst = wot;  N = 1024; roff = 0; }
    const int n0 = bx << 5;
    if (n0 >= N) return;
    const int k0 = by << 5;
    const int tx = threadIdx.x & 31, ty = threadIdx.x >> 5;
#pragma unroll
    for (int r = 0; r < 32; r += 8)
      tile[ty + r][tx] = src[(size_t)(k0 + ty + r) * N + n0 + tx];
    __syncthreads();
#pragma unroll
    for (int r = 0; r < 32; r += 8)
      dst[((size_t)(roff + n0 + ty + r) << 10) + k0 + tx] = f2bf(tile[tx][ty + r]);
  }
}

// ---------------- GEMM: C[M][N] = A[M][K] @ Bt[N][K]^T, tile 128x64, 1D grid + XCD swizzle ----
// mode 0 (nbx=24): block bx = one head: bx<16 Q, 16..19 K (x8-interleave transpose), 20..23 V (transposed [d][t]).
// mode 1 (nbx=16): bias epilogue -> f32 out.
__global__ __launch_bounds__(256) void gemm_kernel(
    const u16* __restrict__ A, const u16* __restrict__ Bt, int K, int mode,
    const float* __restrict__ bias_cat, u16* __restrict__ qbuf, u16* __restrict__ kbufT,
    u16* __restrict__ vbufT, const float* __restrict__ bo, float* __restrict__ outp,
    const float* __restrict__ cosT, const float* __restrict__ sinT,
    const float* __restrict__ hw)
{
  __shared__ alignas(16) char ldsA[16384];
  __shared__ alignas(16) char ldsB[8192];
  const int tid = threadIdx.x;
  const int lane = tid & 63, wid = tid >> 6;
  const int l15 = lane & 15, lg = lane >> 4;
  const int wm = wid << 5;
  const size_t K_ = (size_t)K;

  // bijective XCD swizzle (gridDim.x % 8 == 0): contiguous chunk per XCD
  const int nbx = (mode == 0) ? 24 : 16;
  const int cpx = gridDim.x >> 3;
  const int swz = (blockIdx.x & 7) * cpx + (blockIdx.x >> 3);
  const int bx = swz % nbx;
  const int by = swz / nbx;

  const u16* Apan = A + (size_t)by * 128 * K_;
  const u16* Bpan = Bt + (size_t)bx * 64 * K_;

  f32x4 acc[2][4];
  const f32x4 fz = {0.f, 0.f, 0.f, 0.f};
#pragma unroll
  for (int mt = 0; mt < 2; ++mt)
#pragma unroll
    for (int nt = 0; nt < 4; ++nt) acc[mt][nt] = fz;

  for (int k0 = 0; k0 < K; k0 += 64) {
#pragma unroll
    for (int i = 0; i < 4; ++i) {
      const int grp = i * 4 + wid;            // wave-uniform group [0,16)
      const int c = grp * 64 + lane;
      const int r = c >> 3, k8 = (c & 7) << 3;
      const u16* ga = Apan + (size_t)r * K_ + k0 + k8;
      __builtin_amdgcn_global_load_lds((const GLB void*)ga, (LDS void*)(ldsA + grp * 1024), 16, 0, 0);
      if (i < 2) {
        const u16* gb = Bpan + (size_t)r * K_ + k0 + k8;
        __builtin_amdgcn_global_load_lds((const GLB void*)gb, (LDS void*)(ldsB + grp * 1024), 16, 0, 0);
      }
    }
    __syncthreads();
#pragma unroll
    for (int ks = 0; ks < 2; ++ks) {
      const int kbyte = ks * 64 + lg * 16;
      bf16x8 af[2], bfr[4];
#pragma unroll
      for (int mt = 0; mt < 2; ++mt)
        af[mt] = *(const bf16x8*)(ldsA + (wm + mt * 16 + l15) * 128 + kbyte);
#pragma unroll
      for (int nt = 0; nt < 4; ++nt)
        bfr[nt] = *(const bf16x8*)(ldsB + (nt * 16 + l15) * 128 + kbyte);
#pragma unroll
      for (int mt = 0; mt < 2; ++mt)
#pragma unroll
        for (int nt = 0; nt < 4; ++nt)
          acc[mt][nt] = __builtin_amdgcn_mfma_f32_16x16x32_bf16(af[mt], bfr[nt], acc[mt][nt], 0, 0, 0);
    }
    __syncthreads();
  }

  const int rb = by * 128 + wm + (lg << 2);

  if (mode == 0) {
    const bool isQ = (bx < 16);
    const bool isV = (bx >= 20);
    const float hws = isQ ? hw[bx] * 0.125f : 1.0f;
    float bia[4];
#pragma unroll
    for (int nt = 0; nt < 4; ++nt) bia[nt] = bias_cat[bx * 64 + l15 + nt * 16];
    if (isV) {
#pragma unroll
      for (int mt = 0; mt < 2; ++mt) {
        const int r0 = rb + mt * 16;
        const int bb = r0 >> 11, t0 = r0 & 2047;
        const size_t base = ((size_t)(bb * 4 + (bx - 20))) << 17;
#pragma unroll
        for (int nt = 0; nt < 4; ++nt) {
          u16x4 pk;
#pragma unroll
          for (int j = 0; j < 4; ++j) pk[j] = f2bf(acc[mt][nt][j] + bia[nt]);
          const int d = l15 + nt * 16;
          *(u16x4*)(vbufT + base + (size_t)d * 2048 + t0) = pk;
        }
      }
    } else {
#pragma unroll
      for (int mt = 0; mt < 2; ++mt) {
#pragma unroll
        for (int j = 0; j < 4; ++j) {
          const int r = rb + mt * 16 + j;
          const int bb = r >> 11, t = r & 2047;
          float z[4];
#pragma unroll
          for (int nt = 0; nt < 4; ++nt) z[nt] = acc[mt][nt][j] + bia[nt];
          const float c0 = cosT[(t << 5) + l15],      s0 = sinT[(t << 5) + l15];
          const float c1 = cosT[(t << 5) + l15 + 16], s1 = sinT[(t << 5) + l15 + 16];
          const float n0 = (z[0] * c0 - z[2] * s0) * hws;
          const float n2 = (z[2] * c0 + z[0] * s0) * hws;
          const float n1 = (z[1] * c1 - z[3] * s1) * hws;
          const float n3 = (z[3] * c1 + z[1] * s1) * hws;
          z[0] = n0; z[1] = n1; z[2] = n2; z[3] = n3;
#pragma unroll
          for (int nt = 0; nt < 4; ++nt) {
            const int d = l15 + nt * 16;
            const u16 val = f2bf(z[nt]);
            if (isQ) {
              qbuf[(((size_t)(bb * 16 + bx) * 2048 + t) << 6) + d] = val;
            } else {
              kbufT[(((size_t)(bb * 4 + (bx - 16))) << 17) + ((d >> 3) << 14) + (t << 3) + (d & 7)] = val;
            }
          }
        }
      }
    }
  } else {
#pragma unroll
    for (int nt = 0; nt < 4; ++nt) {
      const int c = bx * 64 + l15 + nt * 16;
      const float bias = bo[c];
#pragma unroll
      for (int mt = 0; mt < 2; ++mt) {
#pragma unroll
        for (int j = 0; j < 4; ++j) {
          const int r = rb + mt * 16 + j;
          outp[(size_t)r * 1024 + c] = acc[mt][nt][j] + bias;
        }
      }
    }
  }
}

// ---------------- combined attention ----------------
// Band blocks [0,1024): wave = 16 rows x 1 head, full-MFMA QK^T + PV (R23-verified).
// Glob blocks [1024,1536): wave = one (kc, hkv, i<8, b) 64-key partial (R23-verified globp).
__global__ __launch_bounds__(256) void attn_comb_kernel(
    const u16* __restrict__ qbuf, const u16* __restrict__ kbufT,
    const u16* __restrict__ vbufT, u16* __restrict__ obuf,
    float* __restrict__ pm, float* __restrict__ pl, float* __restrict__ po)
{
  __shared__ alignas(16) u16 plds[4][16][64];
  const int tid = threadIdx.x;
  const int lane = tid & 63, w = tid >> 6;
  const int l15 = lane & 15, lg = lane >> 4;
  const f32x4 fz = {0.f, 0.f, 0.f, 0.f};
  u16* pw = (u16*)plds[w];

  if (blockIdx.x < 1024) {
    // ---------------- band path ----------------
    const int gw = blockIdx.x * 4 + w;   // [0, 4096): (b, h, k)
    const int k = gw & 127;
    const int h = (gw >> 7) & 15;
    const int b = gw >> 11;
    const int i0 = 8 + k * 16;
    const int a = i0 - 16;
    const int hkv = h >> 2;

    const u16* KpT = kbufT + (((size_t)(b * 4 + hkv)) << 17);
    const u16* VpT = vbufT + (((size_t)(b * 4 + hkv)) << 17);
    const u16* Qp  = qbuf + (((size_t)(b * 16 + h)) << 17);   // [t][d]

    bf16x8 qa[2];
#pragma unroll
    for (int ch = 0; ch < 2; ++ch)
      qa[ch] = *(const bf16x8*)(Qp + (size_t)(i0 + l15) * 64 + ch * 32 + lg * 8);

    int slotj[4];
#pragma unroll
    for (int mt = 0; mt < 4; ++mt) {
      const int t = mt * 16 + l15;
      int j = (t < 8) ? t : a + t - 8;
      slotj[mt] = j < 0 ? 0 : (j > 2047 ? 2047 : j);
    }

    f32x4 s[4];
#pragma unroll
    for (int mt = 0; mt < 4; ++mt) s[mt] = fz;
#pragma unroll
    for (int ch = 0; ch < 2; ++ch) {
#pragma unroll
      for (int mt = 0; mt < 4; ++mt) {
        bf16x8 kf = *(const bf16x8*)(KpT + ((size_t)(ch * 4 + lg) << 14) + (slotj[mt] << 3));
        s[mt] = __builtin_amdgcn_mfma_f32_16x16x32_bf16(qa[ch], kf, s[mt], 0, 0, 0);
      }
    }

#pragma unroll
    for (int mt = 0; mt < 4; ++mt) {
      const int t = mt * 16 + l15;
      const int j = (t < 8) ? t : a + t - 8;
#pragma unroll
      for (int jr = 0; jr < 4; ++jr) {
        const int i = i0 + lg * 4 + jr;
        bool ok;
        if (t < 8) ok = true;
        else ok = (j >= 8) && (j < 2048) && (j >= i - 12) && (j <= i + 12);
        if (!ok) s[mt][jr] = -1e30f;
      }
    }
    float pinvl[4];
#pragma unroll
    for (int jr = 0; jr < 4; ++jr) {
      float m = fmaxf(fmaxf(s[0][jr], s[1][jr]), fmaxf(s[2][jr], s[3][jr]));
#pragma unroll
      for (int sh = 1; sh <= 8; sh <<= 1) m = fmaxf(m, __shfl_xor(m, sh));
      float sum = 0.f;
#pragma unroll
      for (int mt = 0; mt < 4; ++mt) {
        const float p = __expf(s[mt][jr] - m);
        s[mt][jr] = p;
        sum += p;
      }
#pragma unroll
      for (int sh = 1; sh <= 8; sh <<= 1) sum += __shfl_xor(sum, sh);
      pinvl[jr] = 1.f / sum;
    }

#pragma unroll
    for (int mt = 0; mt < 4; ++mt) {
      const int t = mt * 16 + l15;
#pragma unroll
      for (int jr = 0; jr < 4; ++jr) {
        const int q = lg * 4 + jr;
        pw[q * 64 + (t ^ ((q & 7) << 3))] = f2bf(s[mt][jr] * pinvl[jr]);
      }
    }

    bf16x8 paf[2];
#pragma unroll
    for (int ch = 0; ch < 2; ++ch)
      paf[ch] = *(const bf16x8*)(pw + l15 * 64 + ((ch * 32 + lg * 8) ^ ((l15 & 7) << 3)));

    f32x4 oacc[4];
#pragma unroll
    for (int db = 0; db < 4; ++db) oacc[db] = fz;
    __builtin_amdgcn_s_setprio(1);
#pragma unroll
    for (int db = 0; db < 4; ++db) {
#pragma unroll
      for (int ch = 0; ch < 2; ++ch) {
        const int sl0 = ch * 32 + lg * 8;
        int j0 = (sl0 < 8) ? 0 : a + sl0 - 8;
        j0 = j0 < 0 ? 0 : (j0 > 2040 ? 2040 : j0);
        bf16x8 vf = *(const bf16x8*)(VpT + (size_t)(db * 16 + l15) * 2048 + j0);
        oacc[db] = __builtin_amdgcn_mfma_f32_16x16x32_bf16(paf[ch], vf, oacc[db], 0, 0, 0);
      }
    }
    __builtin_amdgcn_s_setprio(0);

#pragma unroll
    for (int jr = 0; jr < 4; ++jr) {
      const int i = i0 + lg * 4 + jr;
      if (i < 2048) {
        const size_t rowo = ((size_t)(b * 2048 + i)) << 10;
#pragma unroll
        for (int db = 0; db < 4; ++db)
          obuf[rowo + h * 64 + db * 16 + l15] = f2bf(oacc[db][jr]);
      }
    }
  } else {
    // ---------------- glob partial path ----------------
    const int u = (blockIdx.x - 1024) * 4 + w;   // [0,2048)
    const int kc = u & 31;
    const int yi = (u >> 5) & 31;
    const int b = u >> 10;
    const int hkv = yi & 3;
    const int i = yi >> 2;
    const u16* KpT = kbufT + (((size_t)(b * 4 + hkv)) << 17);
    const u16* VpT = vbufT + (((size_t)(b * 4 + hkv)) << 17);
    const u16* Qr0 = qbuf + ((((size_t)(b * 16 + hkv * 4 + 0)) * 2048 + i) << 6);
    const u16* Qr1 = qbuf + ((((size_t)(b * 16 + hkv * 4 + 1)) * 2048 + i) << 6);
    const u16* Qr2 = qbuf + ((((size_t)(b * 16 + hkv * 4 + 2)) * 2048 + i) << 6);
    const u16* Qr3 = qbuf + ((((size_t)(b * 16 + hkv * 4 + 3)) * 2048 + i) << 6);

    const int j = (kc << 6) + lane;
    float s0 = 0.f, s1 = 0.f, s2 = 0.f, s3 = 0.f;
#pragma unroll
    for (int d8 = 0; d8 < 8; ++d8) {
      u16x8 k8 = *(const u16x8*)(KpT + (d8 << 14) + (j << 3));
      u16x8 q0 = *(const u16x8*)(Qr0 + d8 * 8);
      u16x8 q1 = *(const u16x8*)(Qr1 + d8 * 8);
      u16x8 q2 = *(const u16x8*)(Qr2 + d8 * 8);
      u16x8 q3 = *(const u16x8*)(Qr3 + d8 * 8);
      s0 = dot8(k8, q0, s0);
      s1 = dot8(k8, q1, s1);
      s2 = dot8(k8, q2, s2);
      s3 = dot8(k8, q3, s3);
    }
    float m0 = s0, m1 = s1, m2 = s2, m3 = s3;
#pragma unroll
    for (int sh = 32; sh >= 1; sh >>= 1) {
      m0 = fmaxf(m0, __shfl_xor(m0, sh));
      m1 = fmaxf(m1, __shfl_xor(m1, sh));
      m2 = fmaxf(m2, __shfl_xor(m2, sh));
      m3 = fmaxf(m3, __shfl_xor(m3, sh));
    }
    float p0 = __expf(s0 - m0), p1 = __expf(s1 - m1), p2 = __expf(s2 - m2), p3 = __expf(s3 - m3);
    float l0 = p0, l1 = p1, l2 = p2, l3 = p3;
#pragma unroll
    for (int sh = 32; sh >= 1; sh >>= 1) {
      l0 += __shfl_xor(l0, sh);
      l1 += __shfl_xor(l1, sh);
      l2 += __shfl_xor(l2, sh);
      l3 += __shfl_xor(l3, sh);
    }

    pw[0 * 64 + (lane ^ 0)]  = f2bf(p0);
    pw[1 * 64 + (lane ^ 8)]  = f2bf(p1);
    pw[2 * 64 + (lane ^ 16)] = f2bf(p2);
    pw[3 * 64 + (lane ^ 24)] = f2bf(p3);

    bf16x8 paf[2];
#pragma unroll
    for (int ch = 0; ch < 2; ++ch)
      paf[ch] = *(const bf16x8*)(pw + l15 * 64 + ((ch * 32 + lg * 8) ^ ((l15 & 7) << 3)));

    f32x4 oacc[4];
#pragma unroll
    for (int db = 0; db < 4; ++db) oacc[db] = fz;
#pragma unroll
    for (int db = 0; db < 4; ++db) {
#pragma unroll
      for (int ch = 0; ch < 2; ++ch) {
        const int j0 = (kc << 6) + ch * 32 + lg * 8;
        bf16x8 vf = *(const bf16x8*)(VpT + (size_t)(db * 16 + l15) * 2048 + j0);
        oacc[db] = __builtin_amdgcn_mfma_f32_16x16x32_bf16(paf[ch], vf, oacc[db], 0, 0, 0);
      }
    }

    const int part = (((b * 4 + hkv) * 8 + i) << 5) + kc;
    if (lane == 0) {
      pm[part * 4 + 0] = m0; pm[part * 4 + 1] = m1; pm[part * 4 + 2] = m2; pm[part * 4 + 3] = m3;
      pl[part * 4 + 0] = l0; pl[part * 4 + 1] = l1; pl[part * 4 + 2] = l2; pl[part * 4 + 3] = l3;
    }
    if (lg == 0) {
      float* pob = po + (((size_t)part << 2) << 6);
#pragma unroll
      for (int db = 0; db < 4; ++db)
#pragma unroll
        for (int h = 0; h < 4; ++h)
          pob[h * 64 + db * 16 + l15] = oacc[db][h];
    }
  }
}

// ---------------- global rows i<8, phase 2: merge 32 partials per (row, head) ----------
__global__ __launch_bounds__(256) void attn_globm_kernel(
    const float* __restrict__ pm, const float* __restrict__ pl,
    const float* __restrict__ po, u16* __restrict__ obuf)
{
  const int idx = blockIdx.x;   // [0,64): (b,hkv,i)
  const int i = idx & 7;
  const int hkv = (idx >> 3) & 3;
  const int b = idx >> 5;
  const int tid = threadIdx.x;
  const int lane = tid & 63, h = tid >> 6;
  const int base = ((b * 4 + hkv) * 8 + i) << 5;

  float M = -1e30f;
#pragma unroll 8
  for (int kc = 0; kc < 32; ++kc) M = fmaxf(M, pm[(base + kc) * 4 + h]);
  float L = 0.f, O = 0.f;
#pragma unroll 8
  for (int kc = 0; kc < 32; ++kc) {
    float sc = __expf(pm[(base + kc) * 4 + h] - M);
    L += pl[(base + kc) * 4 + h] * sc;
    O = fmaf(po[((((size_t)(base + kc) << 2) + h) << 6) + lane], sc, O);
  }
  obuf[(((size_t)(b * 2048 + i)) << 10) + (hkv * 4 + h) * 64 + lane] = f2bf(O / L);
}

extern "C" void kernel_launch(void* const* d_in, const int* in_sizes, int n_in,
                              void* d_out, int out_size, void* d_ws, size_t ws_size,
                              hipStream_t stream) {
  const float* x  = (const float*)d_in[0];
  const float* Wq = (const float*)d_in[1];
  const float* bq = (const float*)d_in[2];
  const float* Wk = (const float*)d_in[3];
  const float* bk = (const float*)d_in[4];
  const float* Wv = (const float*)d_in[5];
  const float* bv = (const float*)d_in[6];
  const float* Wo = (const float*)d_in[7];
  const float* bo = (const float*)d_in[8];
  const float* hw = (const float*)d_in[9];
  float* out = (float*)d_out;

  char* ws = (char*)d_ws;
  size_t off = 0;
  auto alloc = [&](size_t bytes) { char* p = ws + off; off += (bytes + 255) & ~(size_t)255; return p; };
  u16* xbf    = (u16*)alloc((size_t)4096 * 1024 * 2);   // also reused as obuf
  u16* wcat   = (u16*)alloc((size_t)1536 * 1024 * 2);
  u16* wot    = (u16*)alloc((size_t)1024 * 1024 * 2);
  float* biascat = (float*)alloc(1536 * 4);
  float* cosT = (float*)alloc(65536 * 4);
  float* sinT = (float*)alloc(65536 * 4);
  u16* qbuf   = (u16*)alloc((size_t)2 * 16 * 2048 * 64 * 2);
  u16* kbufT  = (u16*)alloc((size_t)2 * 4 * 2048 * 64 * 2);
  u16* vbufT  = (u16*)alloc((size_t)2 * 4 * 2048 * 64 * 2);
  float* pm   = (float*)alloc((size_t)2048 * 4 * 4);
  float* pl   = (float*)alloc((size_t)2048 * 4 * 4);
  float* po   = (float*)alloc((size_t)2048 * 4 * 64 * 4);
  u16* obuf   = xbf;  // xbf dead after first GEMM

  prepw_kernel<<<8454, 256, 0, stream>>>(x, bq, bk, bv, biascat, cosT, sinT, xbf,
                                         Wq, Wk, Wv, Wo, wcat, wot);
  gemm_kernel<<<768, 256, 0, stream>>>(xbf, wcat, 1024, 0, biascat, qbuf, kbufT, vbufT,
                                       nullptr, nullptr, cosT, sinT, hw);
  attn_comb_kernel<<<1536, 256, 0, stream>>>(qbuf, kbufT, vbufT, obuf, pm, pl, po);
  attn_globm_kernel<<<64, 256, 0, stream>>>(pm, pl, po, obuf);
  gemm_kernel<<<512, 256, 0, stream>>>(obuf, wot, 1024, 1, nullptr, nullptr, nullptr,
                                       nullptr, bo, out, nullptr, nullptr, nullptr);
}